// Round 1
// 203.870 us; speedup vs baseline: 1.0160x; 1.0160x over previous
//
#include <hip/hip_runtime.h>
#include <cmath>

// MultimodalCrossAttention on MI355X (gfx950), bf16 MFMA pipeline.
// B=2, Sx=Sc=2048, D_MODEL=1024, H=16, hd=64.

typedef __bf16 bf16x8 __attribute__((ext_vector_type(8)));
typedef __bf16 bf16x4 __attribute__((ext_vector_type(4)));
typedef float f32x4 __attribute__((ext_vector_type(4)));

#define MFMA(A, B, C) __builtin_amdgcn_mfma_f32_16x16x32_bf16(A, B, C, 0, 0, 0)
#define GLL16(g, l)                                                        \
  __builtin_amdgcn_global_load_lds(                                        \
      (const __attribute__((address_space(1))) unsigned int*)(g),          \
      (__attribute__((address_space(3))) unsigned int*)(l), 16, 0, 0)

// ---------------- fused fp32 -> bf16 convert, 2 float4/thread ----------------
__global__ __launch_bounds__(256) void cvt_all_kernel(
    const float* __restrict__ x, const float* __restrict__ ctx,
    const float* __restrict__ Wq, const float* __restrict__ Wv,
    const float* __restrict__ Wo, __bf16* __restrict__ xb, __bf16* __restrict__ cb,
    __bf16* __restrict__ Wqb, __bf16* __restrict__ Wvb, __bf16* __restrict__ Wob) {
  int base = blockIdx.x * 512 + threadIdx.x;
  const float* src;
  __bf16* dst;
  int off;
  if (base < 1048576) { src = x; dst = xb; off = 0; }
  else if (base < 2097152) { src = ctx; dst = cb; off = 1048576; }
  else if (base < 2359296) { src = Wq; dst = Wqb; off = 2097152; }
  else if (base < 2621440) { src = Wv; dst = Wvb; off = 2359296; }
  else { src = Wo; dst = Wob; off = 2621440; }
#pragma unroll
  for (int jj = 0; jj < 2; jj++) {
    int j = base - off + jj * 256;
    float4 f = ((const float4*)src)[j];
    bf16x4 o;
    o[0] = (__bf16)f.x; o[1] = (__bf16)f.y; o[2] = (__bf16)f.z; o[3] = (__bf16)f.w;
    ((bf16x4*)dst)[j] = o;
  }
}

// ---------------- Projection GEMM: 128x128, triple-buffered, XCD-swizzled ----------------
// (unchanged — proven)
__global__ __launch_bounds__(256) void gemm_proj(const __bf16* __restrict__ A0,
                                                 const __bf16* __restrict__ W0,
                                                 void* __restrict__ outQ,
                                                 void* __restrict__ outK,
                                                 void* __restrict__ outV) {
  const int tid = threadIdx.x;
  const int wave = tid >> 6, lane = tid & 63, quad = lane >> 4, l15 = lane & 15;
  const int mw = wave >> 1, nw = wave & 1;

  const int id = blockIdx.x;
  int m0, n0;
  const __bf16* A;
  const __bf16* W;
  bool vmode;
  if (id < 512) {
    const int xcd = id & 7, j = id >> 3;
    m0 = (xcd * 8 + (j & 7)) * 128;
    n0 = (j >> 3) * 128;
    A = A0;                              // xb||cb, rows 0..8191
    W = W0;                              // Wqb
    vmode = false;
  } else {
    const int vid = id - 512;
    const int xcd = vid & 7, j = vid >> 3;
    m0 = (xcd * 4 + (j & 3)) * 128;
    n0 = (j >> 2) * 128;
    A = A0 + (size_t)4096 * 1024;        // cb
    W = W0 + (size_t)1024 * 1024;        // Wvb
    vmode = true;
  }

  __shared__ __attribute__((aligned(16))) __bf16 As[3][4096];  // 24KB
  __shared__ __attribute__((aligned(16))) __bf16 Ws[3][4096];  // 24KB

  int goff[2];
#pragma unroll
  for (int jj = 0; jj < 2; jj++) {
    const int s = jj * 256 + tid;
    const int row = s >> 2;
    const int kcg = (s & 3) ^ ((row >> 1) & 3);
    goff[jj] = row * 1024 + kcg * 8;
  }
  const __bf16* Ag = A + (size_t)m0 * 1024;
  const __bf16* Wg = W + (size_t)n0 * 1024;
  const int ldsoff0 = wave * 512;
  const int ldsoff1 = 2048 + wave * 512;

  const int sw = (l15 >> 1) & 3;
  int afoff[4], wfoff[4];
#pragma unroll
  for (int t = 0; t < 4; t++) {
    afoff[t] = (mw * 64 + t * 16 + l15) * 32 + (quad ^ sw) * 8;
    wfoff[t] = (nw * 64 + t * 16 + l15) * 32 + (quad ^ sw) * 8;
  }

  f32x4 acc[4][4] = {};

  auto stage = [&](int buf, int k0) {
    GLL16(Ag + goff[0] + k0, &As[buf][ldsoff0]);
    GLL16(Ag + goff[1] + k0, &As[buf][ldsoff1]);
    GLL16(Wg + goff[0] + k0, &Ws[buf][ldsoff0]);
    GLL16(Wg + goff[1] + k0, &Ws[buf][ldsoff1]);
  };
  auto compute = [&](int buf) {
    bf16x8 af[4], wf[4];
#pragma unroll
    for (int t = 0; t < 4; t++) af[t] = *(const bf16x8*)&As[buf][afoff[t]];
#pragma unroll
    for (int t = 0; t < 4; t++) wf[t] = *(const bf16x8*)&Ws[buf][wfoff[t]];
#pragma unroll
    for (int mt = 0; mt < 4; mt++)
#pragma unroll
      for (int nt = 0; nt < 4; nt++) acc[mt][nt] = MFMA(af[mt], wf[nt], acc[mt][nt]);
  };

  stage(0, 0);
  stage(1, 32);
  int buf = 0;
  for (int c = 0; c < 32; c++) {
    __syncthreads();
    if (c + 2 < 32) {
      int nb = buf + 2;
      if (nb >= 3) nb -= 3;
      stage(nb, (c + 2) * 32);
    }
    compute(buf);
    buf = (buf == 2) ? 0 : buf + 1;
  }

  // Epilogue. C/D: row = quad*4+r (per 16-tile), col = l15.
  if (!vmode) {
    const int isK = (m0 >= 4096);
    __bf16* O = (__bf16*)(isK ? outK : outQ);
    const float qsc = isK ? 1.0f : 0.18033688f;  // 0.125*log2(e) folded into Q
    const int mb = m0 & 4095;
#pragma unroll
    for (int nt = 0; nt < 4; nt++) {
      const int n = n0 + nw * 64 + nt * 16 + l15;
      const int h = n >> 6, d = n & 63, p = d >> 1;
      const float invf_rev =
          __builtin_amdgcn_exp2f(-((float)p * 0.41524101f + 2.6514961f));
#pragma unroll
      for (int mt = 0; mt < 4; mt++) {
#pragma unroll
        for (int r = 0; r < 4; r++) {
          const int row = mb + mw * 64 + mt * 16 + quad * 4 + r;
          const int s = row & 2047, b = row >> 11;
          float v = acc[mt][nt][r];
          float pv = __shfl_xor(v, 1, 64);
          float fr = __builtin_amdgcn_fractf((float)s * invf_rev);
          float sn = __builtin_amdgcn_sinf(fr);
          float cs = __builtin_amdgcn_cosf(fr);
          float res = (lane & 1) ? (pv * sn + v * cs) : (v * cs - pv * sn);
          O[((size_t)(b * 16 + h) * 2048 + s) * 64 + d] = (__bf16)(res * qsc);
        }
      }
    }
  } else {
    __bf16* O = (__bf16*)outV;
#pragma unroll
    for (int nt = 0; nt < 4; nt++) {
      const int n = n0 + nw * 64 + nt * 16 + l15;
      const int h = n >> 6, d = n & 63;
#pragma unroll
      for (int mt = 0; mt < 4; mt++) {
        const int rowb = m0 + mw * 64 + mt * 16 + quad * 4;
        const int s = rowb & 2047, b = rowb >> 11;
        bf16x4 o;
#pragma unroll
        for (int r = 0; r < 4; r++) o[r] = (__bf16)acc[mt][nt][r];
        *(bf16x4*)(O + ((size_t)(b * 16 + h) * 64 + d) * 2048 + s) = o;
      }
    }
  }
}

// ---------------- Out-proj GEMM: 128x64 tile, triple-buffered, XCD-swizzled ----------------
// Rebuilt as a gemm_proj clone. Grid 512 (2 blocks/CU): xcd=id&7, j=id>>3:
// m0=(xcd*4+(j&3))*128, n0=(j>>2)*64. Per-XCD: A-slice 1MB + Wo 2MB = L2-resident.
// Per wave: 8 MFMA / 6 ds_read_b128 per K-step (vs old 64x64: 4/4). LDS 36KB.
__global__ __launch_bounds__(256) void gemm_out(const __bf16* __restrict__ A,
                                                const __bf16* __restrict__ W,
                                                float* __restrict__ O,
                                                const float* __restrict__ bias) {
  const int tid = threadIdx.x;
  const int wave = tid >> 6, lane = tid & 63, quad = lane >> 4, l15 = lane & 15;
  const int mw = wave >> 1, nw = wave & 1;
  const int id = blockIdx.x;
  const int xcd = id & 7, j = id >> 3;       // j 0..63
  const int m0 = (xcd * 4 + (j & 3)) * 128;  // 32 m-tiles
  const int n0 = (j >> 2) * 64;              // 16 n-tiles

  __shared__ __attribute__((aligned(16))) __bf16 As[3][4096];  // 24KB
  __shared__ __attribute__((aligned(16))) __bf16 Ws[3][2048];  // 12KB

  int goff[2];
#pragma unroll
  for (int jj = 0; jj < 2; jj++) {
    const int s = jj * 256 + tid;
    const int row = s >> 2;
    const int kcg = (s & 3) ^ ((row >> 1) & 3);
    goff[jj] = row * 1024 + kcg * 8;
  }
  // W tile is 64 rows x 32 k: one GLL16 per wave covers it.
  const int wrow = tid >> 2;
  const int wkcg = (tid & 3) ^ ((wrow >> 1) & 3);
  const int goffw = wrow * 1024 + wkcg * 8;

  const __bf16* Ag = A + (size_t)m0 * 1024;
  const __bf16* Wg = W + (size_t)n0 * 1024;
  const int ldsoff0 = wave * 512;
  const int ldsoff1 = 2048 + wave * 512;

  const int sw = (l15 >> 1) & 3;
  int afoff[4], wfoff[2];
#pragma unroll
  for (int t = 0; t < 4; t++)
    afoff[t] = (mw * 64 + t * 16 + l15) * 32 + (quad ^ sw) * 8;
#pragma unroll
  for (int t = 0; t < 2; t++)
    wfoff[t] = (nw * 32 + t * 16 + l15) * 32 + (quad ^ sw) * 8;

  f32x4 acc[4][2] = {};

  auto stage = [&](int buf, int k0) {
    GLL16(Ag + goff[0] + k0, &As[buf][ldsoff0]);
    GLL16(Ag + goff[1] + k0, &As[buf][ldsoff1]);
    GLL16(Wg + goffw + k0, &Ws[buf][ldsoff0]);
  };
  auto compute = [&](int buf) {
    bf16x8 af[4], wf[2];
#pragma unroll
    for (int t = 0; t < 4; t++) af[t] = *(const bf16x8*)&As[buf][afoff[t]];
#pragma unroll
    for (int t = 0; t < 2; t++) wf[t] = *(const bf16x8*)&Ws[buf][wfoff[t]];
#pragma unroll
    for (int mt = 0; mt < 4; mt++)
#pragma unroll
      for (int nt = 0; nt < 2; nt++) acc[mt][nt] = MFMA(af[mt], wf[nt], acc[mt][nt]);
  };

  stage(0, 0);
  stage(1, 32);
  int buf = 0;
  for (int c = 0; c < 32; c++) {
    __syncthreads();
    if (c + 2 < 32) {
      int nb = buf + 2;
      if (nb >= 3) nb -= 3;
      stage(nb, (c + 2) * 32);
    }
    compute(buf);
    buf = (buf == 2) ? 0 : buf + 1;
  }

#pragma unroll
  for (int nt = 0; nt < 2; nt++) {
    const int n = n0 + nw * 32 + nt * 16 + l15;
    const float bv = bias[n];
#pragma unroll
    for (int mt = 0; mt < 4; mt++) {
#pragma unroll
      for (int r = 0; r < 4; r++) {
        const int row = m0 + mw * 64 + mt * 16 + quad * 4 + r;
        O[(size_t)row * 1024 + n] = acc[mt][nt][r] + bv;
      }
    }
  }
}

// ---------------- Flash attention: BQ=128, 8 waves x 16 q-rows, quad-buffered K/V ----------------
// Same tile/swizzle/LDS layout as the proven 4-wave version, but the 128 q-rows are
// split across 8 waves (512 threads). Same grid (512 blocks), same 80KB LDS ->
// 2 blocks/CU now carry 16 waves/CU = 4 waves/SIMD (was 2) for latency hiding.
__global__ __launch_bounds__(512) void attn_kernel(const __bf16* __restrict__ Q,
                                                   const __bf16* __restrict__ K,
                                                   const __bf16* __restrict__ Vt,
                                                   __bf16* __restrict__ Aout) {
  const int tid = threadIdx.x;
  const int wave = tid >> 6, lane = tid & 63, quad = lane >> 4, l15 = lane & 15;
  const int id = blockIdx.x;
  const int j = id >> 3;
  const int bh = ((id & 7) << 2) | (j & 3);
  const int q0 = (j >> 2) << 7;

  const __bf16* Qb = Q + (size_t)bh * (2048 * 64);
  const __bf16* Kb = K + (size_t)bh * (2048 * 64);
  const __bf16* Vb = Vt + (size_t)bh * (64 * 2048);

  __shared__ __attribute__((aligned(16))) __bf16 Kbuf[4][4096];     // 32KB
  __shared__ __attribute__((aligned(16))) __bf16 Vbuf[4][4096];     // 32KB
  __shared__ __attribute__((aligned(16))) __bf16 Plds[8][8][16][8]; // 16KB

  bf16x8 qf[2];
  {
    const __bf16* qp = Qb + (size_t)(q0 + wave * 16 + l15) * 64 + quad * 8;
    qf[0] = *(const bf16x8*)qp;
    qf[1] = *(const bf16x8*)(qp + 32);
  }

  // staging: each of 8 waves stages 512 elems of K and V per buffer
  const int s0 = wave * 64 + lane;
  const int r0 = s0 >> 3, c0 = (s0 & 7) ^ (r0 & 7);
  const __bf16* kg0 = Kb + r0 * 64 + c0 * 8;
  const __bf16* vg0 = Vb + r0 * 2048 + c0 * 8;
  const int klds = wave * 512;

  const int offF0 = l15 * 64 + ((quad ^ (l15 & 7)) * 8);
  const int offF1 = l15 * 64 + (((4 + quad) ^ (l15 & 7)) * 8);

  f32x4 rs4 = {};
  f32x4 oT[4] = {};

  auto stage = [&](int buf, int kt) {
    GLL16(kg0 + kt * 64, &Kbuf[buf][klds]);
    GLL16(vg0 + kt, &Vbuf[buf][klds]);
  };
  auto compute = [&](int buf) {
    f32x4 sT[4];
#pragma unroll
    for (int nt = 0; nt < 4; nt++) {
      bf16x8 kf0 = *(const bf16x8*)&Kbuf[buf][nt * 1024 + offF0];
      bf16x8 kf1 = *(const bf16x8*)&Kbuf[buf][nt * 1024 + offF1];
      f32x4 z = {};
      z = MFMA(kf0, qf[0], z);
      sT[nt] = MFMA(kf1, qf[1], z);
    }
#pragma unroll
    for (int nt = 0; nt < 4; nt++) {
      bf16x4 pb;
      f32x4 pe;
#pragma unroll
      for (int r = 0; r < 4; r++) {
        pe[r] = __builtin_amdgcn_exp2f(sT[nt][r]);
        pb[r] = (__bf16)pe[r];
      }
      rs4 += pe;
      const int chunk = nt * 2 + (quad >> 1);
      *(bf16x4*)&Plds[wave][chunk][l15 ^ ((chunk & 3) << 1)][(quad & 1) * 4] = pb;
    }
    bf16x8 pf0 = *(const bf16x8*)&Plds[wave][quad][l15 ^ (quad << 1)][0];
    bf16x8 pf1 = *(const bf16x8*)&Plds[wave][4 + quad][l15 ^ (quad << 1)][0];
#pragma unroll
    for (int nt = 0; nt < 4; nt++) {
      bf16x8 vf0 = *(const bf16x8*)&Vbuf[buf][nt * 1024 + offF0];
      bf16x8 vf1 = *(const bf16x8*)&Vbuf[buf][nt * 1024 + offF1];
      oT[nt] = MFMA(vf0, pf0, oT[nt]);
      oT[nt] = MFMA(vf1, pf1, oT[nt]);
    }
  };

  stage(0, 0);
  stage(1, 64);
  for (int kt = 0; kt < 2048; kt += 128) {
    const int p = (kt >> 7) & 1;
    __syncthreads();
    if (kt + 128 < 2048) {
      stage(2 * (p ^ 1), kt + 128);
      stage(2 * (p ^ 1) + 1, kt + 192);
    }
    compute(2 * p);
    compute(2 * p + 1);
  }

  const int b = bh >> 4, h = bh & 15;
  float l = (rs4[0] + rs4[1]) + (rs4[2] + rs4[3]);
  l += __shfl_xor(l, 16, 64);
  l += __shfl_xor(l, 32, 64);
  const float inv = 1.f / l;
  const int q = q0 + wave * 16 + l15;
#pragma unroll
  for (int nt = 0; nt < 4; nt++) {
    bf16x4 o;
#pragma unroll
    for (int r = 0; r < 4; r++) o[r] = (__bf16)(oT[nt][r] * inv);
    *(bf16x4*)&Aout[((size_t)(b * 2048 + q)) * 1024 + h * 64 + nt * 16 + quad * 4] = o;
  }
}

extern "C" void kernel_launch(void* const* d_in, const int* in_sizes, int n_in,
                              void* d_out, int out_size, void* d_ws, size_t ws_size,
                              hipStream_t stream) {
  const float* x   = (const float*)d_in[0];
  const float* ctx = (const float*)d_in[1];
  const float* Wq  = (const float*)d_in[2];
  const float* Wv  = (const float*)d_in[3];
  const float* Wo  = (const float*)d_in[4];
  const float* bo  = (const float*)d_in[5];

  char* ws = (char*)d_ws;
  const size_t MB = 1024 * 1024;
  __bf16* xb   = (__bf16*)(ws + 0 * MB);   // [4096,1024]; contiguous with cb
  __bf16* cb   = (__bf16*)(ws + 8 * MB);   // [4096,1024]
  __bf16* Wqb  = (__bf16*)(ws + 16 * MB);  // contiguous with Wvb
  __bf16* Wvb  = (__bf16*)(ws + 18 * MB);
  __bf16* Wob  = (__bf16*)(ws + 20 * MB);
  __bf16* qh   = (__bf16*)(ws + 22 * MB);  // [b,h,s,d], pre-scaled by 0.18034
  __bf16* kh   = (__bf16*)(ws + 30 * MB);  // [b,h,s,d]
  __bf16* vt   = (__bf16*)(ws + 38 * MB);  // [b,h,d,s]
  __bf16* attn = xb;  // xb dead after QK projection

  cvt_all_kernel<<<5632, 256, 0, stream>>>(x, ctx, Wq, Wv, Wo, xb, cb, Wqb, Wvb, Wob);

  gemm_proj<<<768, 256, 0, stream>>>(xb, Wqb, (void*)qh, (void*)kh, (void*)vt);

  attn_kernel<<<512, 512, 0, stream>>>(qh, kh, vt, attn);

  gemm_out<<<512, 256, 0, stream>>>(attn, Wob, (float*)d_out, bo);
}

// Round 2
// 201.690 us; speedup vs baseline: 1.0270x; 1.0108x over previous
//
#include <hip/hip_runtime.h>
#include <cmath>

// MultimodalCrossAttention on MI355X (gfx950), bf16 MFMA pipeline.
// B=2, Sx=Sc=2048, D_MODEL=1024, H=16, hd=64.

typedef __bf16 bf16x8 __attribute__((ext_vector_type(8)));
typedef __bf16 bf16x4 __attribute__((ext_vector_type(4)));
typedef float f32x4 __attribute__((ext_vector_type(4)));
typedef float f32x16 __attribute__((ext_vector_type(16)));
typedef unsigned u32x4v __attribute__((ext_vector_type(4)));

#define MFMA(A, B, C) __builtin_amdgcn_mfma_f32_16x16x32_bf16(A, B, C, 0, 0, 0)
#define MFMA32(A, B, C) __builtin_amdgcn_mfma_f32_32x32x16_bf16(A, B, C, 0, 0, 0)
#define GLL16(g, l)                                                        \
  __builtin_amdgcn_global_load_lds(                                        \
      (const __attribute__((address_space(1))) unsigned int*)(g),          \
      (__attribute__((address_space(3))) unsigned int*)(l), 16, 0, 0)

// ---------------- fused fp32 -> bf16 convert, 2 float4/thread ----------------
__global__ __launch_bounds__(256) void cvt_all_kernel(
    const float* __restrict__ x, const float* __restrict__ ctx,
    const float* __restrict__ Wq, const float* __restrict__ Wv,
    const float* __restrict__ Wo, __bf16* __restrict__ xb, __bf16* __restrict__ cb,
    __bf16* __restrict__ Wqb, __bf16* __restrict__ Wvb, __bf16* __restrict__ Wob) {
  int base = blockIdx.x * 512 + threadIdx.x;
  const float* src;
  __bf16* dst;
  int off;
  if (base < 1048576) { src = x; dst = xb; off = 0; }
  else if (base < 2097152) { src = ctx; dst = cb; off = 1048576; }
  else if (base < 2359296) { src = Wq; dst = Wqb; off = 2097152; }
  else if (base < 2621440) { src = Wv; dst = Wvb; off = 2359296; }
  else { src = Wo; dst = Wob; off = 2621440; }
#pragma unroll
  for (int jj = 0; jj < 2; jj++) {
    int j = base - off + jj * 256;
    float4 f = ((const float4*)src)[j];
    bf16x4 o;
    o[0] = (__bf16)f.x; o[1] = (__bf16)f.y; o[2] = (__bf16)f.z; o[3] = (__bf16)f.w;
    ((bf16x4*)dst)[j] = o;
  }
}

// ---------------- Projection GEMM: 128x128, triple-buffered, XCD-swizzled ----------------
// (unchanged — proven)
__global__ __launch_bounds__(256) void gemm_proj(const __bf16* __restrict__ A0,
                                                 const __bf16* __restrict__ W0,
                                                 void* __restrict__ outQ,
                                                 void* __restrict__ outK,
                                                 void* __restrict__ outV) {
  const int tid = threadIdx.x;
  const int wave = tid >> 6, lane = tid & 63, quad = lane >> 4, l15 = lane & 15;
  const int mw = wave >> 1, nw = wave & 1;

  const int id = blockIdx.x;
  int m0, n0;
  const __bf16* A;
  const __bf16* W;
  bool vmode;
  if (id < 512) {
    const int xcd = id & 7, j = id >> 3;
    m0 = (xcd * 8 + (j & 7)) * 128;
    n0 = (j >> 3) * 128;
    A = A0;                              // xb||cb, rows 0..8191
    W = W0;                              // Wqb
    vmode = false;
  } else {
    const int vid = id - 512;
    const int xcd = vid & 7, j = vid >> 3;
    m0 = (xcd * 4 + (j & 3)) * 128;
    n0 = (j >> 2) * 128;
    A = A0 + (size_t)4096 * 1024;        // cb
    W = W0 + (size_t)1024 * 1024;        // Wvb
    vmode = true;
  }

  __shared__ __attribute__((aligned(16))) __bf16 As[3][4096];  // 24KB
  __shared__ __attribute__((aligned(16))) __bf16 Ws[3][4096];  // 24KB

  int goff[2];
#pragma unroll
  for (int jj = 0; jj < 2; jj++) {
    const int s = jj * 256 + tid;
    const int row = s >> 2;
    const int kcg = (s & 3) ^ ((row >> 1) & 3);
    goff[jj] = row * 1024 + kcg * 8;
  }
  const __bf16* Ag = A + (size_t)m0 * 1024;
  const __bf16* Wg = W + (size_t)n0 * 1024;
  const int ldsoff0 = wave * 512;
  const int ldsoff1 = 2048 + wave * 512;

  const int sw = (l15 >> 1) & 3;
  int afoff[4], wfoff[4];
#pragma unroll
  for (int t = 0; t < 4; t++) {
    afoff[t] = (mw * 64 + t * 16 + l15) * 32 + (quad ^ sw) * 8;
    wfoff[t] = (nw * 64 + t * 16 + l15) * 32 + (quad ^ sw) * 8;
  }

  f32x4 acc[4][4] = {};

  auto stage = [&](int buf, int k0) {
    GLL16(Ag + goff[0] + k0, &As[buf][ldsoff0]);
    GLL16(Ag + goff[1] + k0, &As[buf][ldsoff1]);
    GLL16(Wg + goff[0] + k0, &Ws[buf][ldsoff0]);
    GLL16(Wg + goff[1] + k0, &Ws[buf][ldsoff1]);
  };
  auto compute = [&](int buf) {
    bf16x8 af[4], wf[4];
#pragma unroll
    for (int t = 0; t < 4; t++) af[t] = *(const bf16x8*)&As[buf][afoff[t]];
#pragma unroll
    for (int t = 0; t < 4; t++) wf[t] = *(const bf16x8*)&Ws[buf][wfoff[t]];
#pragma unroll
    for (int mt = 0; mt < 4; mt++)
#pragma unroll
      for (int nt = 0; nt < 4; nt++) acc[mt][nt] = MFMA(af[mt], wf[nt], acc[mt][nt]);
  };

  stage(0, 0);
  stage(1, 32);
  int buf = 0;
  for (int c = 0; c < 32; c++) {
    __syncthreads();
    if (c + 2 < 32) {
      int nb = buf + 2;
      if (nb >= 3) nb -= 3;
      stage(nb, (c + 2) * 32);
    }
    compute(buf);
    buf = (buf == 2) ? 0 : buf + 1;
  }

  // Epilogue. C/D: row = quad*4+r (per 16-tile), col = l15.
  if (!vmode) {
    const int isK = (m0 >= 4096);
    __bf16* O = (__bf16*)(isK ? outK : outQ);
    const float qsc = isK ? 1.0f : 0.18033688f;  // 0.125*log2(e) folded into Q
    const int mb = m0 & 4095;
#pragma unroll
    for (int nt = 0; nt < 4; nt++) {
      const int n = n0 + nw * 64 + nt * 16 + l15;
      const int h = n >> 6, d = n & 63, p = d >> 1;
      const float invf_rev =
          __builtin_amdgcn_exp2f(-((float)p * 0.41524101f + 2.6514961f));
#pragma unroll
      for (int mt = 0; mt < 4; mt++) {
#pragma unroll
        for (int r = 0; r < 4; r++) {
          const int row = mb + mw * 64 + mt * 16 + quad * 4 + r;
          const int s = row & 2047, b = row >> 11;
          float v = acc[mt][nt][r];
          float pv = __shfl_xor(v, 1, 64);
          float fr = __builtin_amdgcn_fractf((float)s * invf_rev);
          float sn = __builtin_amdgcn_sinf(fr);
          float cs = __builtin_amdgcn_cosf(fr);
          float res = (lane & 1) ? (pv * sn + v * cs) : (v * cs - pv * sn);
          O[((size_t)(b * 16 + h) * 2048 + s) * 64 + d] = (__bf16)(res * qsc);
        }
      }
    }
  } else {
    __bf16* O = (__bf16*)outV;
#pragma unroll
    for (int nt = 0; nt < 4; nt++) {
      const int n = n0 + nw * 64 + nt * 16 + l15;
      const int h = n >> 6, d = n & 63;
#pragma unroll
      for (int mt = 0; mt < 4; mt++) {
        const int rowb = m0 + mw * 64 + mt * 16 + quad * 4;
        const int s = rowb & 2047, b = rowb >> 11;
        bf16x4 o;
#pragma unroll
        for (int r = 0; r < 4; r++) o[r] = (__bf16)acc[mt][nt][r];
        *(bf16x4*)(O + ((size_t)(b * 16 + h) * 64 + d) * 2048 + s) = o;
      }
    }
  }
}

// ---------------- Out-proj GEMM: 128x64 tile, triple-buffered, XCD-swizzled ----------------
__global__ __launch_bounds__(256) void gemm_out(const __bf16* __restrict__ A,
                                                const __bf16* __restrict__ W,
                                                float* __restrict__ O,
                                                const float* __restrict__ bias) {
  const int tid = threadIdx.x;
  const int wave = tid >> 6, lane = tid & 63, quad = lane >> 4, l15 = lane & 15;
  const int mw = wave >> 1, nw = wave & 1;
  const int id = blockIdx.x;
  const int xcd = id & 7, j = id >> 3;       // j 0..63
  const int m0 = (xcd * 4 + (j & 3)) * 128;  // 32 m-tiles
  const int n0 = (j >> 2) * 64;              // 16 n-tiles

  __shared__ __attribute__((aligned(16))) __bf16 As[3][4096];  // 24KB
  __shared__ __attribute__((aligned(16))) __bf16 Ws[3][2048];  // 12KB

  int goff[2];
#pragma unroll
  for (int jj = 0; jj < 2; jj++) {
    const int s = jj * 256 + tid;
    const int row = s >> 2;
    const int kcg = (s & 3) ^ ((row >> 1) & 3);
    goff[jj] = row * 1024 + kcg * 8;
  }
  const int wrow = tid >> 2;
  const int wkcg = (tid & 3) ^ ((wrow >> 1) & 3);
  const int goffw = wrow * 1024 + wkcg * 8;

  const __bf16* Ag = A + (size_t)m0 * 1024;
  const __bf16* Wg = W + (size_t)n0 * 1024;
  const int ldsoff0 = wave * 512;
  const int ldsoff1 = 2048 + wave * 512;

  const int sw = (l15 >> 1) & 3;
  int afoff[4], wfoff[2];
#pragma unroll
  for (int t = 0; t < 4; t++)
    afoff[t] = (mw * 64 + t * 16 + l15) * 32 + (quad ^ sw) * 8;
#pragma unroll
  for (int t = 0; t < 2; t++)
    wfoff[t] = (nw * 32 + t * 16 + l15) * 32 + (quad ^ sw) * 8;

  f32x4 acc[4][2] = {};

  auto stage = [&](int buf, int k0) {
    GLL16(Ag + goff[0] + k0, &As[buf][ldsoff0]);
    GLL16(Ag + goff[1] + k0, &As[buf][ldsoff1]);
    GLL16(Wg + goffw + k0, &Ws[buf][ldsoff0]);
  };
  auto compute = [&](int buf) {
    bf16x8 af[4], wf[2];
#pragma unroll
    for (int t = 0; t < 4; t++) af[t] = *(const bf16x8*)&As[buf][afoff[t]];
#pragma unroll
    for (int t = 0; t < 2; t++) wf[t] = *(const bf16x8*)&Ws[buf][wfoff[t]];
#pragma unroll
    for (int mt = 0; mt < 4; mt++)
#pragma unroll
      for (int nt = 0; nt < 2; nt++) acc[mt][nt] = MFMA(af[mt], wf[nt], acc[mt][nt]);
  };

  stage(0, 0);
  stage(1, 32);
  int buf = 0;
  for (int c = 0; c < 32; c++) {
    __syncthreads();
    if (c + 2 < 32) {
      int nb = buf + 2;
      if (nb >= 3) nb -= 3;
      stage(nb, (c + 2) * 32);
    }
    compute(buf);
    buf = (buf == 2) ? 0 : buf + 1;
  }

#pragma unroll
  for (int nt = 0; nt < 2; nt++) {
    const int n = n0 + nw * 32 + nt * 16 + l15;
    const float bv = bias[n];
#pragma unroll
    for (int mt = 0; mt < 4; mt++) {
#pragma unroll
      for (int r = 0; r < 4; r++) {
        const int row = m0 + mw * 64 + mt * 16 + quad * 4 + r;
        O[(size_t)row * 1024 + n] = acc[mt][nt][r] + bv;
      }
    }
  }
}

// ---------------- Flash attention: 32x32 MFMA, in-register P (cvt_pk+permlane) ----------------
// 8 waves = 4 q-groups (32 q) x 2 k-groups (32 k of each 64-row K-tile).
// QK: S^T = MFMA32(K, Q) -> lane col = q, reg row = k (crow(r,hi)=(r&3)+8*(r>>2)+4*hi).
// P->bf16 PV-A-frag in-register: 8 v_cvt_pk_bf16_f32 + 4 v_permlane32_swap_b32 per tile
// (no P LDS round-trip). K/V frag reads halve vs 16x16 (32 FLOP/B). LDS 64KB, 2 blk/CU.
// End: cross-kg O/l reduction through LDS (Kbuf/Vbuf reused).
__global__ __launch_bounds__(512, 4) void attn_kernel(const __bf16* __restrict__ Q,
                                                      const __bf16* __restrict__ K,
                                                      const __bf16* __restrict__ Vt,
                                                      __bf16* __restrict__ Aout) {
  const int tid = threadIdx.x;
  const int wave = tid >> 6, lane = tid & 63;
  const int l31 = lane & 31, hi = lane >> 5;
  const int qg = wave >> 1, kg = wave & 1;
  const int id = blockIdx.x;
  const int j = id >> 3;
  const int bh = ((id & 7) << 2) | (j & 3);
  const int q0 = (j >> 2) << 7;

  const __bf16* Qb = Q + (size_t)bh * (2048 * 64);
  const __bf16* Kb = K + (size_t)bh * (2048 * 64);
  const __bf16* Vb = Vt + (size_t)bh * (64 * 2048);

  __shared__ __attribute__((aligned(16))) __bf16 Kbuf[4][4096];  // 32KB
  __shared__ __attribute__((aligned(16))) __bf16 Vbuf[4][4096];  // 32KB

  // Q B-fragments: lane holds q = q0+qg*32+l31, d = i*16 + hi*8 + [0..8)
  bf16x8 qf[4];
  {
    const __bf16* qp = Qb + (size_t)(q0 + qg * 32 + l31) * 64 + hi * 8;
#pragma unroll
    for (int i = 0; i < 4; i++) qf[i] = *(const bf16x8*)(qp + i * 16);
  }

  // staging: each of 8 waves stages 1KB of K and V per 64-row buffer
  const int s0 = wave * 64 + lane;
  const int r0 = s0 >> 3, c0 = (s0 & 7) ^ (r0 & 7);
  const __bf16* kgp = Kb + r0 * 64 + c0 * 8;
  const __bf16* vgp = Vb + r0 * 2048 + c0 * 8;
  const int klds = wave * 512;

  // K A-frag offsets: row rk = kg*32+l31, col-group g = 2i+hi (8-col xor swizzle)
  int koff[4];
  {
    const int rk = kg * 32 + l31;
#pragma unroll
    for (int i = 0; i < 4; i++) koff[i] = rk * 64 + (((2 * i + hi) ^ (rk & 7)) * 8);
  }
  // V B-frag offsets: row rv = dt*32+l31 (d), col-group g = kg*4 + ks*2 + hi (s)
  int voff[2][2];
#pragma unroll
  for (int dt = 0; dt < 2; dt++) {
    const int rv = dt * 32 + l31;
#pragma unroll
    for (int ks = 0; ks < 2; ks++)
      voff[dt][ks] = rv * 64 + (((kg * 4 + ks * 2 + hi) ^ (rv & 7)) * 8);
  }

  f32x4 rs4 = {};
  f32x16 oacc[2] = {};

  auto stage = [&](int buf, int kt) {
    GLL16(kgp + kt * 64, &Kbuf[buf][klds]);
    GLL16(vgp + kt, &Vbuf[buf][klds]);
  };

  auto compute = [&](int buf) {
    f32x16 s = {};
#pragma unroll
    for (int i = 0; i < 4; i++) {
      bf16x8 kf = *(const bf16x8*)&Kbuf[buf][koff[i]];
      s = MFMA32(kf, qf[i], s);
    }
    float pe[16];
#pragma unroll
    for (int r = 0; r < 16; r++) pe[r] = __builtin_amdgcn_exp2f(s[r]);
#pragma unroll
    for (int r = 0; r < 16; r++) rs4[r & 3] += pe[r];
    // pack P into PV A-fragments, in-register (T12)
    bf16x8 pa[2];
#pragma unroll
    for (int sl = 0; sl < 2; sl++) {
      unsigned wa, wb, wc, wd;
      asm("v_cvt_pk_bf16_f32 %0, %1, %2" : "=v"(wa) : "v"(pe[8 * sl + 0]), "v"(pe[8 * sl + 1]));
      asm("v_cvt_pk_bf16_f32 %0, %1, %2" : "=v"(wb) : "v"(pe[8 * sl + 4]), "v"(pe[8 * sl + 5]));
      asm("v_cvt_pk_bf16_f32 %0, %1, %2" : "=v"(wc) : "v"(pe[8 * sl + 2]), "v"(pe[8 * sl + 3]));
      asm("v_cvt_pk_bf16_f32 %0, %1, %2" : "=v"(wd) : "v"(pe[8 * sl + 6]), "v"(pe[8 * sl + 7]));
      // swap: a.hi <-> b.lo  => a = {a.lo,b.lo} (word0), b = {a.hi,b.hi} (word2)
      asm("v_permlane32_swap_b32 %0, %1" : "+v"(wa), "+v"(wb));
      asm("v_permlane32_swap_b32 %0, %1" : "+v"(wc), "+v"(wd));
      u32x4v t;
      t[0] = wa; t[1] = wc; t[2] = wb; t[3] = wd;
      pa[sl] = __builtin_bit_cast(bf16x8, t);
    }
    // PV: O[q][d] += P[q][k] V[k][d]
#pragma unroll
    for (int dt = 0; dt < 2; dt++)
#pragma unroll
      for (int ks = 0; ks < 2; ks++) {
        bf16x8 vf = *(const bf16x8*)&Vbuf[buf][voff[dt][ks]];
        oacc[dt] = MFMA32(pa[ks], vf, oacc[dt]);
      }
  };

  stage(0, 0);
  stage(1, 64);
  for (int kt = 0; kt < 2048; kt += 128) {
    const int p = (kt >> 7) & 1;
    __syncthreads();
    if (kt + 128 < 2048) {
      stage(2 * (p ^ 1), kt + 128);
      stage(2 * (p ^ 1) + 1, kt + 192);
    }
    compute(2 * p);
    compute(2 * p + 1);
  }

  // ---- cross-kg reduction (Kbuf/Vbuf reused as f32 scratch) ----
  __syncthreads();
  float* Ored = (float*)&Kbuf[0][0];  // [4 qg][32 slot][64 lane] f32 = 32KB
  float* Lred = (float*)&Vbuf[0][0];  // [8 wave][64 lane] f32 = 2KB

  float lw = (rs4[0] + rs4[1]) + (rs4[2] + rs4[3]);
  lw += __shfl_xor(lw, 32, 64);
  Lred[wave * 64 + lane] = lw;
  if (kg == 1) {
#pragma unroll
    for (int dt = 0; dt < 2; dt++)
#pragma unroll
      for (int r = 0; r < 16; r++)
        Ored[(qg * 32 + dt * 16 + r) * 64 + lane] = oacc[dt][r];
  }
  __syncthreads();
  if (kg == 0) {
    const int b = bh >> 4, h = bh & 15;
#pragma unroll
    for (int r = 0; r < 16; r++) {
      const int qrow = (r & 3) + 8 * (r >> 2) + 4 * hi;
      const float lt =
          Lred[(qg * 2) * 64 + qrow] + Lred[(qg * 2 + 1) * 64 + qrow];
      const float inv = 1.f / lt;
      const int qAbs = q0 + qg * 32 + qrow;
#pragma unroll
      for (int dt = 0; dt < 2; dt++) {
        const float o = oacc[dt][r] + Ored[(qg * 32 + dt * 16 + r) * 64 + lane];
        Aout[((size_t)(b * 2048 + qAbs)) * 1024 + h * 64 + dt * 32 + l31] =
            (__bf16)(o * inv);
      }
    }
  }
}

extern "C" void kernel_launch(void* const* d_in, const int* in_sizes, int n_in,
                              void* d_out, int out_size, void* d_ws, size_t ws_size,
                              hipStream_t stream) {
  const float* x   = (const float*)d_in[0];
  const float* ctx = (const float*)d_in[1];
  const float* Wq  = (const float*)d_in[2];
  const float* Wv  = (const float*)d_in[3];
  const float* Wo  = (const float*)d_in[4];
  const float* bo  = (const float*)d_in[5];

  char* ws = (char*)d_ws;
  const size_t MB = 1024 * 1024;
  __bf16* xb   = (__bf16*)(ws + 0 * MB);   // [4096,1024]; contiguous with cb
  __bf16* cb   = (__bf16*)(ws + 8 * MB);   // [4096,1024]
  __bf16* Wqb  = (__bf16*)(ws + 16 * MB);  // contiguous with Wvb
  __bf16* Wvb  = (__bf16*)(ws + 18 * MB);
  __bf16* Wob  = (__bf16*)(ws + 20 * MB);
  __bf16* qh   = (__bf16*)(ws + 22 * MB);  // [b,h,s,d], pre-scaled by 0.18034
  __bf16* kh   = (__bf16*)(ws + 30 * MB);  // [b,h,s,d]
  __bf16* vt   = (__bf16*)(ws + 38 * MB);  // [b,h,d,s]
  __bf16* attn = xb;  // xb dead after QK projection

  cvt_all_kernel<<<5632, 256, 0, stream>>>(x, ctx, Wq, Wv, Wo, xb, cb, Wqb, Wvb, Wob);

  gemm_proj<<<768, 256, 0, stream>>>(xb, Wqb, (void*)qh, (void*)kh, (void*)vt);

  attn_kernel<<<512, 512, 0, stream>>>(qh, kh, vt, attn);

  gemm_out<<<512, 256, 0, stream>>>(attn, Wob, (float*)d_out, bo);
}